// Round 18
// baseline (150.549 us; speedup 1.0000x reference)
//
#include <hip/hip_runtime.h>
#include <hip/hip_bf16.h>

// Forbid FMA contraction for plain fp expressions in ALL device code below:
// the kNN ranking must bit-match the reference's uncontracted fp32 expression
//   pd[i,j] = 2*inner(i,j) - xx[i] - xx[j]
// (rounds 4/6/8/10/11/13/14/16/17 passed uncontracted; round 5 regressed when
// the compiler fused 2*inner-xxi into v_fma_f32). Explicit fmaf() calls are
// NOT affected by this pragma -- the approx prefilter exploits exactly that.
#pragma clang fp contract(off)

// B=4, N=4096, C=128, K=32. All fp32. top-K LARGEST pd, tie -> lowest index.
// Round 18: WAVE-PER-QUERY rewrite. knn was pinned at ~87us across VALU -40%
// (r13), VMEM /5 (r17), occ 50->58% -- latency-bound on a barrier-serialized
// critical path with only ~4.6 256-thread blocks/CU overlapping. Now:
//   - 64-thread blocks (1 wave = 1 query): 16-32 independent queries/CU,
//     every __syncthreads is a 1-wave no-op.
//   - two-pass: pass1 = running max only (no pd array); threshold = 32nd
//     largest of the 64 lane-maxima via shuffle bitonic (the 32 largest
//     lane-maxima are 32 distinct elements => m32 <= v32), minus 2^-11
//     margin (covers 2*delta, delta<=1e-4 approx-vs-exact). pass2 = recompute
//     (L1-hot) + gather survivors (E~44, >=32 guaranteed, cap 128).
//   - histogram/scan machinery DELETED. Exact re-key + composite bitonic
//     top-32 (key desc, idx asc) verbatim from the proven rounds.
//   - W-transpose spread over blocks 0..255; linear_v3 (r17) unchanged.

constexpr int NB   = 4;
constexpr int NP   = 4096;
constexpr int NC   = 128;
constexpr int NK   = 32;
constexpr int NT   = 256;   // linear kernel block size

// approx pd for one candidate (fmaf allowed; bounded vs exact by ~1e-4)
__device__ __forceinline__ float pd_approx1(
    float x, float y, float z, float qx, float qy, float qz, float xxi)
{
    const float xxj   = fmaf(x, x, fmaf(y, y, z * z));
    const float inner = fmaf(qx, x, fmaf(qy, y, qz * z));
    return fmaf(2.0f, inner, -xxi) - xxj;
}

// ---------------------------------------------------------------------------
// Kernel A: one wave per query. kNN (two-pass prefilter + exact refine) +
// mean pool. Blocks 0..255 also transpose one 64-elem slice of W -> Wt.
// ---------------------------------------------------------------------------
__global__ __launch_bounds__(64, 8) void knn_wave_kernel(
    const float* __restrict__ xyz,    // [B,3,N]
    const float* __restrict__ feats,  // [B,N,C]
    const float* __restrict__ W,      // [C,C]
    float* __restrict__ Wt,           // [C,C] transposed out (or nullptr)
    float* __restrict__ pooled)       // [B*N, C] (d_out, fp32 temp)
{
    const int bi = blockIdx.x;
    const int b  = bi >> 12;
    const int i  = bi & (NP - 1);
    const int l  = threadIdx.x;       // lane 0..63

    // spread W-transpose over the first 256 blocks (1 coalesced read each)
    if (Wt != nullptr && bi < 256) {
        const int e = bi * 64 + l;
        Wt[(e & (NC - 1)) * NC + (e >> 7)] = W[e];
    }

    const float* xb = xyz + (size_t)b * 3 * NP;
    const float qx  = xb[i];
    const float qy  = xb[NP + i];
    const float qz  = xb[2 * NP + i];
    const float xxi = (qx * qx + qy * qy) + qz * qz;  // uncontracted (exact)

    // -- pass 1: running max of approx pd over 64 candidates (no storage) --
    float tmax = -3.0e38f;
    #pragma unroll
    for (int q = 0; q < 16; ++q) {
        const int j4 = q * 256 + l * 4;
        const float4 X = *(const float4*)&xb[j4];
        const float4 Y = *(const float4*)&xb[NP + j4];
        const float4 Z = *(const float4*)&xb[2 * NP + j4];
        tmax = fmaxf(tmax, pd_approx1(X.x, Y.x, Z.x, qx, qy, qz, xxi));
        tmax = fmaxf(tmax, pd_approx1(X.y, Y.y, Z.y, qx, qy, qz, xxi));
        tmax = fmaxf(tmax, pd_approx1(X.z, Y.z, Z.z, qx, qy, qz, xxi));
        tmax = fmaxf(tmax, pd_approx1(X.w, Y.w, Z.w, qx, qy, qz, xxi));
    }

    // -- bitonic sort (desc) of the 64 lane-maxima; lane r = r-th largest --
    {
        float v = tmax;
        #pragma unroll
        for (int k = 2; k <= 64; k <<= 1) {
            #pragma unroll
            for (int jj = k >> 1; jj >= 1; jj >>= 1) {
                const float o = __shfl_xor(v, jj, 64);
                const bool wantMax = (((l & k) == 0) == ((l & jj) == 0));
                v = (wantMax == (o > v)) ? o : v;
            }
        }
        tmax = v;   // reuse register: sorted value
    }
    const float m32 = __shfl(tmax, 31, 64);   // 32nd largest lane-max
    const float thr = m32 - 0x1p-11f;         // margin >= 2*delta

    __shared__ int      s_sj[128];
    __shared__ unsigned s_sk[128];
    __shared__ int      s_sel[NK];
    __shared__ unsigned s_scnt;

    if (l == 0) s_scnt = 0;
    if (l < NK) s_sel[l] = 0;                 // defensive
    __syncthreads();                          // 1-wave: trivial

    // -- pass 2: recompute (L1-hot) and gather survivors --
    #pragma unroll
    for (int q = 0; q < 16; ++q) {
        const int j4 = q * 256 + l * 4;
        const float4 X = *(const float4*)&xb[j4];
        const float4 Y = *(const float4*)&xb[NP + j4];
        const float4 Z = *(const float4*)&xb[2 * NP + j4];
        const float p0 = pd_approx1(X.x, Y.x, Z.x, qx, qy, qz, xxi);
        const float p1 = pd_approx1(X.y, Y.y, Z.y, qx, qy, qz, xxi);
        const float p2 = pd_approx1(X.z, Y.z, Z.z, qx, qy, qz, xxi);
        const float p3 = pd_approx1(X.w, Y.w, Z.w, qx, qy, qz, xxi);
        if (p0 >= thr) { const unsigned p = atomicAdd(&s_scnt, 1u); if (p < 128u) s_sj[p] = j4 + 0; }
        if (p1 >= thr) { const unsigned p = atomicAdd(&s_scnt, 1u); if (p < 128u) s_sj[p] = j4 + 1; }
        if (p2 >= thr) { const unsigned p = atomicAdd(&s_scnt, 1u); if (p < 128u) s_sj[p] = j4 + 2; }
        if (p3 >= thr) { const unsigned p = atomicAdd(&s_scnt, 1u); if (p < 128u) s_sj[p] = j4 + 3; }
    }
    __syncthreads();

    const int sc = (int)min(s_scnt, 128u);    // >= 32 always (subset property)

    // -- exact re-key: uncontracted reference bits, survivors only --
    for (int s = l; s < sc; s += 64) {
        const int j = s_sj[s];
        const float px = xb[j];
        const float py = xb[NP + j];
        const float pz = xb[2 * NP + j];
        const float xxj   = (px * px + py * py) + pz * pz;   // no FMA (pragma)
        const float inner = (qx * px + qy * py) + qz * pz;   // no FMA (pragma)
        const float pd    = (2.0f * inner - xxi) - xxj;      // no FMA (pragma)
        const unsigned u  = __float_as_uint(pd);
        s_sk[s] = (u & 0x80000000u) ? ~u : (u | 0x80000000u);
    }
    __syncthreads();

    // -- exact top-32 among survivors by (key desc, idx asc) --
    if (sc <= 64) {
        unsigned long long comp = 0ull;       // padding sorts below all real
        if (l < sc)
            comp = ((unsigned long long)s_sk[l] << 32) |
                   (unsigned)(~(unsigned)s_sj[l]);
        #pragma unroll
        for (int k = 2; k <= 64; k <<= 1) {
            #pragma unroll
            for (int jj = k >> 1; jj >= 1; jj >>= 1) {
                const unsigned long long other = __shfl_xor(comp, jj, 64);
                const bool wantMax = (((l & k) == 0) == ((l & jj) == 0));
                comp = (wantMax == (other > comp)) ? other : comp;
            }
        }
        if (l < NK)
            s_sel[l] = (int)(~(unsigned)(comp & 0xffffffffull));
    } else {
        // rare path (65..128 survivors): 2 composites/lane, 32 extractions
        unsigned long long c0 = 0ull, c1 = 0ull;
        if (l < sc)
            c0 = ((unsigned long long)s_sk[l] << 32) |
                 (unsigned)(~(unsigned)s_sj[l]);
        if (l + 64 < sc)
            c1 = ((unsigned long long)s_sk[l + 64] << 32) |
                 (unsigned)(~(unsigned)s_sj[l + 64]);
        for (int r = 0; r < NK; ++r) {
            unsigned long long w = (c0 > c1) ? c0 : c1;
            #pragma unroll
            for (int off = 32; off >= 1; off >>= 1) {
                const unsigned long long o = __shfl_xor(w, off, 64);
                if (o > w) w = o;
            }
            if (c0 == w) c0 = 0ull; else if (c1 == w) c1 = 0ull;
            if (l == 0)
                s_sel[r] = (int)(~(unsigned)(w & 0xffffffffull));
        }
    }
    __syncthreads();

    // -- mean-pool: lane = (4-ch group cg, 16-row half rg); shfl fold --
    const int cg = l & 31;    // channels 4*cg .. 4*cg+3
    const int rg = l >> 5;    // rows rg*16 .. rg*16+15
    const float* fb = feats + (size_t)b * NP * NC;
    float ax = 0.f, ay = 0.f, az = 0.f, aw = 0.f;
    #pragma unroll
    for (int k = 0; k < 16; ++k) {
        const int j = s_sel[rg * 16 + k] & (NP - 1);   // fault-proof mask
        const float4 f = *(const float4*)&fb[(size_t)j * NC + cg * 4];
        ax += f.x; ay += f.y; az += f.z; aw += f.w;
    }
    const float bx = __shfl_down(ax, 32, 64);
    const float by = __shfl_down(ay, 32, 64);
    const float bz = __shfl_down(az, 32, 64);
    const float bw = __shfl_down(aw, 32, 64);
    if (l < 32) {
        const float inv = 1.0f / (float)NK;
        float4 s;
        s.x = (ax + bx) * inv;
        s.y = (ay + by) * inv;
        s.z = (az + bz) * inv;
        s.w = (aw + bw) * inv;
        *(float4*)&pooled[(size_t)bi * NC + l * 4] = s;
    }
}

// ---------------------------------------------------------------------------
// Kernel B (v3, r17-verbatim): in-place Linear, 512 blocks x 32 rows.
// ---------------------------------------------------------------------------
constexpr int LROWS = 32;
__global__ __launch_bounds__(NT) void linear_v3_kernel(
    float* __restrict__ io,           // [B*N, C] fp32, in-place
    const float* __restrict__ Wt)     // [C, C] transposed: Wt[c][d]
{
    const int t    = threadIdx.x;
    const int row0 = blockIdx.x * LROWS;

    __shared__ float P[LROWS * NC];   // 16 KiB

    const float4* src4 = (const float4*)(io + (size_t)row0 * NC);
    #pragma unroll
    for (int m = 0; m < 4; ++m)
        ((float4*)P)[m * NT + t] = src4[m * NT + t];
    __syncthreads();

    const int dg = t & 31;            // d = 4*dg .. 4*dg+3
    const int rg = t >> 5;            // rows 4*rg .. 4*rg+3

    float4 a0 = make_float4(0.f,0.f,0.f,0.f);
    float4 a1 = make_float4(0.f,0.f,0.f,0.f);
    float4 a2 = make_float4(0.f,0.f,0.f,0.f);
    float4 a3 = make_float4(0.f,0.f,0.f,0.f);
    const float4* Wt4 = (const float4*)Wt;   // row c = 32 float4
    const float*  Pr  = P + rg * 4 * NC;

#define LSTEP(K, PC)                                                          \
    {                                                                         \
        const float4 w = Wt4[(c4 * 4 + K) * 32 + dg];                         \
        a0.x = fmaf(p0.PC, w.x, a0.x); a0.y = fmaf(p0.PC, w.y, a0.y);         \
        a0.z = fmaf(p0.PC, w.z, a0.z); a0.w = fmaf(p0.PC, w.w, a0.w);         \
        a1.x = fmaf(p1.PC, w.x, a1.x); a1.y = fmaf(p1.PC, w.y, a1.y);         \
        a1.z = fmaf(p1.PC, w.z, a1.z); a1.w = fmaf(p1.PC, w.w, a1.w);         \
        a2.x = fmaf(p2.PC, w.x, a2.x); a2.y = fmaf(p2.PC, w.y, a2.y);         \
        a2.z = fmaf(p2.PC, w.z, a2.z); a2.w = fmaf(p2.PC, w.w, a2.w);         \
        a3.x = fmaf(p3.PC, w.x, a3.x); a3.y = fmaf(p3.PC, w.y, a3.y);         \
        a3.z = fmaf(p3.PC, w.z, a3.z); a3.w = fmaf(p3.PC, w.w, a3.w);         \
    }

    #pragma unroll 4
    for (int c4 = 0; c4 < NC / 4; ++c4) {
        const float4 p0 = *(const float4*)&Pr[c4 * 4];            // b128 reads
        const float4 p1 = *(const float4*)&Pr[NC + c4 * 4];
        const float4 p2 = *(const float4*)&Pr[2 * NC + c4 * 4];
        const float4 p3 = *(const float4*)&Pr[3 * NC + c4 * 4];
        LSTEP(0, x) LSTEP(1, y) LSTEP(2, z) LSTEP(3, w)
    }
#undef LSTEP

    float4* dst4 = (float4*)(io + (size_t)row0 * NC);
    const int r4 = rg * 4;
    dst4[(r4 + 0) * 32 + dg] = a0;    // all staging reads done pre-barrier
    dst4[(r4 + 1) * 32 + dg] = a1;
    dst4[(r4 + 2) * 32 + dg] = a2;
    dst4[(r4 + 3) * 32 + dg] = a3;
}

// ---------------------------------------------------------------------------
// Fallback (ws-less): old 64-row in-place linear reading W directly.
// ---------------------------------------------------------------------------
__global__ __launch_bounds__(NT) void linear_kernel(
    float* __restrict__ io, const float* __restrict__ W)
{
    const int t = threadIdx.x;
    const int row0 = blockIdx.x * 64;
    __shared__ float P[64 * NC];
    const float* src = io + (size_t)row0 * NC;
    #pragma unroll
    for (int m = 0; m < 8; ++m) {
        const int e4 = m * NT + t;
        *(float4*)&P[e4 * 4] = *(const float4*)&src[e4 * 4];
    }
    __syncthreads();
    const int d = t & (NC - 1);
    const int rbase = (t >> 7) * 32;
    float acc[32];
    #pragma unroll
    for (int k = 0; k < 32; ++k) acc[k] = 0.f;
    const float* Wd = W + (size_t)d * NC;
    for (int c4 = 0; c4 < NC / 4; ++c4) {
        const float4 w = *(const float4*)(Wd + c4 * 4);
        #pragma unroll
        for (int k = 0; k < 32; ++k) {
            const float4 pv = *(const float4*)&P[(rbase + k) * NC + c4 * 4];
            acc[k] = fmaf(pv.x, w.x, acc[k]);
            acc[k] = fmaf(pv.y, w.y, acc[k]);
            acc[k] = fmaf(pv.z, w.z, acc[k]);
            acc[k] = fmaf(pv.w, w.w, acc[k]);
        }
    }
    #pragma unroll
    for (int k = 0; k < 32; ++k)
        io[(size_t)(row0 + rbase + k) * NC + d] = acc[k];
}

// ---------------------------------------------------------------------------
extern "C" void kernel_launch(void* const* d_in, const int* in_sizes, int n_in,
                              void* d_out, int out_size, void* d_ws, size_t ws_size,
                              hipStream_t stream) {
    const float* xyz   = nullptr;  // 49152
    const float* feats = nullptr;  // 2097152
    const float* W     = nullptr;  // 16384
    for (int k = 0; k < n_in; ++k) {
        if      (in_sizes[k] == NB * 3 * NP)       xyz   = (const float*)d_in[k];
        else if (in_sizes[k] == NB * NP * NC)      feats = (const float*)d_in[k];
        else if (in_sizes[k] == NC * NC)           W     = (const float*)d_in[k];
    }
    float* out = (float*)d_out;

    const size_t need = sizeof(float) * (size_t)(NC * NC);
    if (ws_size >= need) {
        float* Wt = (float*)d_ws;                  // 64 KiB
        knn_wave_kernel<<<NB * NP, 64, 0, stream>>>(xyz, feats, W, Wt, out);
        linear_v3_kernel<<<NB * NP / LROWS, NT, 0, stream>>>(out, Wt);
    } else {
        knn_wave_kernel<<<NB * NP, 64, 0, stream>>>(xyz, feats, W, nullptr, out);
        linear_kernel<<<NB * NP / 64, NT, 0, stream>>>(out, W);
    }
}

// Round 19
// 94.010 us; speedup vs baseline: 1.6014x; 1.6014x over previous
//
#include <hip/hip_runtime.h>
#include <hip/hip_bf16.h>

// Forbid FMA contraction for plain fp expressions in ALL device code below:
// the kNN ranking must bit-match the reference's uncontracted fp32 expression
//   pd[i,j] = 2*inner(i,j) - xx[i] - xx[j]
// (rounds 4/6/8/10/11/13/14/16/17/18 passed uncontracted; round 5 regressed
// when the compiler fused 2*inner-xxi into v_fma_f32). Explicit fmaf() calls
// are NOT affected by this pragma -- the approx prefilter exploits that.
#pragma clang fp contract(off)

// B=4, N=4096, C=128, K=32. All fp32. top-K LARGEST pd, tie -> lowest index.
// Round 19: r18 wave-per-query structure, SPILL FIXED. r18's 390MB/dispatch
// HBM traffic (vs 16MB of actual data, all L3-resident) was scratch
// spill/fill: full unroll of the 16-iter loops wanted ~48 float4 in flight
// (~192 VGPR) against launch_bounds(64,8)'s 64-VGPR cap -> ~370B/thread
// spilled. Fix: launch_bounds(64,4) (128 VGPR allowed, still 16 waves/CU)
// + #pragma unroll 4 (max 4 quads in flight ~ 75 VGPR demand).
// r18's occupancy=77%/VALUBusy=36% confirmed the latency-overlap thesis;
// with spill gone this structure should realize it.

constexpr int NB   = 4;
constexpr int NP   = 4096;
constexpr int NC   = 128;
constexpr int NK   = 32;
constexpr int NT   = 256;   // linear kernel block size

// approx pd for one candidate (fmaf allowed; bounded vs exact by ~1e-4)
__device__ __forceinline__ float pd_approx1(
    float x, float y, float z, float qx, float qy, float qz, float xxi)
{
    const float xxj   = fmaf(x, x, fmaf(y, y, z * z));
    const float inner = fmaf(qx, x, fmaf(qy, y, qz * z));
    return fmaf(2.0f, inner, -xxi) - xxj;
}

// ---------------------------------------------------------------------------
// Kernel A: one wave per query. kNN (two-pass prefilter + exact refine) +
// mean pool. Blocks 0..255 also transpose one 64-elem slice of W -> Wt.
// ---------------------------------------------------------------------------
__global__ __launch_bounds__(64, 4) void knn_wave_kernel(
    const float* __restrict__ xyz,    // [B,3,N]
    const float* __restrict__ feats,  // [B,N,C]
    const float* __restrict__ W,      // [C,C]
    float* __restrict__ Wt,           // [C,C] transposed out (or nullptr)
    float* __restrict__ pooled)       // [B*N, C] (d_out, fp32 temp)
{
    const int bi = blockIdx.x;
    const int b  = bi >> 12;
    const int i  = bi & (NP - 1);
    const int l  = threadIdx.x;       // lane 0..63

    // spread W-transpose over the first 256 blocks (1 coalesced read each)
    if (Wt != nullptr && bi < 256) {
        const int e = bi * 64 + l;
        Wt[(e & (NC - 1)) * NC + (e >> 7)] = W[e];
    }

    const float* xb = xyz + (size_t)b * 3 * NP;
    const float qx  = xb[i];
    const float qy  = xb[NP + i];
    const float qz  = xb[2 * NP + i];
    const float xxi = (qx * qx + qy * qy) + qz * qz;  // uncontracted (exact)

    // -- pass 1: running max of approx pd over 64 candidates (no storage) --
    float tmax = -3.0e38f;
    #pragma unroll 4
    for (int q = 0; q < 16; ++q) {
        const int j4 = q * 256 + l * 4;
        const float4 X = *(const float4*)&xb[j4];
        const float4 Y = *(const float4*)&xb[NP + j4];
        const float4 Z = *(const float4*)&xb[2 * NP + j4];
        tmax = fmaxf(tmax, pd_approx1(X.x, Y.x, Z.x, qx, qy, qz, xxi));
        tmax = fmaxf(tmax, pd_approx1(X.y, Y.y, Z.y, qx, qy, qz, xxi));
        tmax = fmaxf(tmax, pd_approx1(X.z, Y.z, Z.z, qx, qy, qz, xxi));
        tmax = fmaxf(tmax, pd_approx1(X.w, Y.w, Z.w, qx, qy, qz, xxi));
    }

    // -- bitonic sort (desc) of the 64 lane-maxima; lane r = r-th largest --
    {
        float v = tmax;
        #pragma unroll
        for (int k = 2; k <= 64; k <<= 1) {
            #pragma unroll
            for (int jj = k >> 1; jj >= 1; jj >>= 1) {
                const float o = __shfl_xor(v, jj, 64);
                const bool wantMax = (((l & k) == 0) == ((l & jj) == 0));
                v = (wantMax == (o > v)) ? o : v;
            }
        }
        tmax = v;   // reuse register: sorted value
    }
    const float m32 = __shfl(tmax, 31, 64);   // 32nd largest lane-max
    const float thr = m32 - 0x1p-11f;         // margin >= 2*delta

    __shared__ int      s_sj[128];
    __shared__ unsigned s_sk[128];
    __shared__ int      s_sel[NK];
    __shared__ unsigned s_scnt;

    if (l == 0) s_scnt = 0;
    if (l < NK) s_sel[l] = 0;                 // defensive
    __syncthreads();                          // 1-wave: trivial

    // -- pass 2: recompute (L1-hot) and gather survivors --
    #pragma unroll 4
    for (int q = 0; q < 16; ++q) {
        const int j4 = q * 256 + l * 4;
        const float4 X = *(const float4*)&xb[j4];
        const float4 Y = *(const float4*)&xb[NP + j4];
        const float4 Z = *(const float4*)&xb[2 * NP + j4];
        const float p0 = pd_approx1(X.x, Y.x, Z.x, qx, qy, qz, xxi);
        const float p1 = pd_approx1(X.y, Y.y, Z.y, qx, qy, qz, xxi);
        const float p2 = pd_approx1(X.z, Y.z, Z.z, qx, qy, qz, xxi);
        const float p3 = pd_approx1(X.w, Y.w, Z.w, qx, qy, qz, xxi);
        if (p0 >= thr) { const unsigned p = atomicAdd(&s_scnt, 1u); if (p < 128u) s_sj[p] = j4 + 0; }
        if (p1 >= thr) { const unsigned p = atomicAdd(&s_scnt, 1u); if (p < 128u) s_sj[p] = j4 + 1; }
        if (p2 >= thr) { const unsigned p = atomicAdd(&s_scnt, 1u); if (p < 128u) s_sj[p] = j4 + 2; }
        if (p3 >= thr) { const unsigned p = atomicAdd(&s_scnt, 1u); if (p < 128u) s_sj[p] = j4 + 3; }
    }
    __syncthreads();

    const int sc = (int)min(s_scnt, 128u);    // >= 32 always (subset property)

    // -- exact re-key: uncontracted reference bits, survivors only --
    for (int s = l; s < sc; s += 64) {
        const int j = s_sj[s];
        const float px = xb[j];
        const float py = xb[NP + j];
        const float pz = xb[2 * NP + j];
        const float xxj   = (px * px + py * py) + pz * pz;   // no FMA (pragma)
        const float inner = (qx * px + qy * py) + qz * pz;   // no FMA (pragma)
        const float pd    = (2.0f * inner - xxi) - xxj;      // no FMA (pragma)
        const unsigned u  = __float_as_uint(pd);
        s_sk[s] = (u & 0x80000000u) ? ~u : (u | 0x80000000u);
    }
    __syncthreads();

    // -- exact top-32 among survivors by (key desc, idx asc) --
    if (sc <= 64) {
        unsigned long long comp = 0ull;       // padding sorts below all real
        if (l < sc)
            comp = ((unsigned long long)s_sk[l] << 32) |
                   (unsigned)(~(unsigned)s_sj[l]);
        #pragma unroll
        for (int k = 2; k <= 64; k <<= 1) {
            #pragma unroll
            for (int jj = k >> 1; jj >= 1; jj >>= 1) {
                const unsigned long long other = __shfl_xor(comp, jj, 64);
                const bool wantMax = (((l & k) == 0) == ((l & jj) == 0));
                comp = (wantMax == (other > comp)) ? other : comp;
            }
        }
        if (l < NK)
            s_sel[l] = (int)(~(unsigned)(comp & 0xffffffffull));
    } else {
        // rare path (65..128 survivors): 2 composites/lane, 32 extractions
        unsigned long long c0 = 0ull, c1 = 0ull;
        if (l < sc)
            c0 = ((unsigned long long)s_sk[l] << 32) |
                 (unsigned)(~(unsigned)s_sj[l]);
        if (l + 64 < sc)
            c1 = ((unsigned long long)s_sk[l + 64] << 32) |
                 (unsigned)(~(unsigned)s_sj[l + 64]);
        for (int r = 0; r < NK; ++r) {
            unsigned long long w = (c0 > c1) ? c0 : c1;
            #pragma unroll
            for (int off = 32; off >= 1; off >>= 1) {
                const unsigned long long o = __shfl_xor(w, off, 64);
                if (o > w) w = o;
            }
            if (c0 == w) c0 = 0ull; else if (c1 == w) c1 = 0ull;
            if (l == 0)
                s_sel[r] = (int)(~(unsigned)(w & 0xffffffffull));
        }
    }
    __syncthreads();

    // -- mean-pool: lane = (4-ch group cg, 16-row half rg); shfl fold --
    const int cg = l & 31;    // channels 4*cg .. 4*cg+3
    const int rg = l >> 5;    // rows rg*16 .. rg*16+15
    const float* fb = feats + (size_t)b * NP * NC;
    float ax = 0.f, ay = 0.f, az = 0.f, aw = 0.f;
    #pragma unroll 4
    for (int k = 0; k < 16; ++k) {
        const int j = s_sel[rg * 16 + k] & (NP - 1);   // fault-proof mask
        const float4 f = *(const float4*)&fb[(size_t)j * NC + cg * 4];
        ax += f.x; ay += f.y; az += f.z; aw += f.w;
    }
    const float bx = __shfl_down(ax, 32, 64);
    const float by = __shfl_down(ay, 32, 64);
    const float bz = __shfl_down(az, 32, 64);
    const float bw = __shfl_down(aw, 32, 64);
    if (l < 32) {
        const float inv = 1.0f / (float)NK;
        float4 s;
        s.x = (ax + bx) * inv;
        s.y = (ay + by) * inv;
        s.z = (az + bz) * inv;
        s.w = (aw + bw) * inv;
        *(float4*)&pooled[(size_t)bi * NC + l * 4] = s;
    }
}

// ---------------------------------------------------------------------------
// Kernel B (v3, r17-verbatim): in-place Linear, 512 blocks x 32 rows.
// ---------------------------------------------------------------------------
constexpr int LROWS = 32;
__global__ __launch_bounds__(NT) void linear_v3_kernel(
    float* __restrict__ io,           // [B*N, C] fp32, in-place
    const float* __restrict__ Wt)     // [C, C] transposed: Wt[c][d]
{
    const int t    = threadIdx.x;
    const int row0 = blockIdx.x * LROWS;

    __shared__ float P[LROWS * NC];   // 16 KiB

    const float4* src4 = (const float4*)(io + (size_t)row0 * NC);
    #pragma unroll
    for (int m = 0; m < 4; ++m)
        ((float4*)P)[m * NT + t] = src4[m * NT + t];
    __syncthreads();

    const int dg = t & 31;            // d = 4*dg .. 4*dg+3
    const int rg = t >> 5;            // rows 4*rg .. 4*rg+3

    float4 a0 = make_float4(0.f,0.f,0.f,0.f);
    float4 a1 = make_float4(0.f,0.f,0.f,0.f);
    float4 a2 = make_float4(0.f,0.f,0.f,0.f);
    float4 a3 = make_float4(0.f,0.f,0.f,0.f);
    const float4* Wt4 = (const float4*)Wt;   // row c = 32 float4
    const float*  Pr  = P + rg * 4 * NC;

#define LSTEP(K, PC)                                                          \
    {                                                                         \
        const float4 w = Wt4[(c4 * 4 + K) * 32 + dg];                         \
        a0.x = fmaf(p0.PC, w.x, a0.x); a0.y = fmaf(p0.PC, w.y, a0.y);         \
        a0.z = fmaf(p0.PC, w.z, a0.z); a0.w = fmaf(p0.PC, w.w, a0.w);         \
        a1.x = fmaf(p1.PC, w.x, a1.x); a1.y = fmaf(p1.PC, w.y, a1.y);         \
        a1.z = fmaf(p1.PC, w.z, a1.z); a1.w = fmaf(p1.PC, w.w, a1.w);         \
        a2.x = fmaf(p2.PC, w.x, a2.x); a2.y = fmaf(p2.PC, w.y, a2.y);         \
        a2.z = fmaf(p2.PC, w.z, a2.z); a2.w = fmaf(p2.PC, w.w, a2.w);         \
        a3.x = fmaf(p3.PC, w.x, a3.x); a3.y = fmaf(p3.PC, w.y, a3.y);         \
        a3.z = fmaf(p3.PC, w.z, a3.z); a3.w = fmaf(p3.PC, w.w, a3.w);         \
    }

    #pragma unroll 4
    for (int c4 = 0; c4 < NC / 4; ++c4) {
        const float4 p0 = *(const float4*)&Pr[c4 * 4];            // b128 reads
        const float4 p1 = *(const float4*)&Pr[NC + c4 * 4];
        const float4 p2 = *(const float4*)&Pr[2 * NC + c4 * 4];
        const float4 p3 = *(const float4*)&Pr[3 * NC + c4 * 4];
        LSTEP(0, x) LSTEP(1, y) LSTEP(2, z) LSTEP(3, w)
    }
#undef LSTEP

    float4* dst4 = (float4*)(io + (size_t)row0 * NC);
    const int r4 = rg * 4;
    dst4[(r4 + 0) * 32 + dg] = a0;    // all staging reads done pre-barrier
    dst4[(r4 + 1) * 32 + dg] = a1;
    dst4[(r4 + 2) * 32 + dg] = a2;
    dst4[(r4 + 3) * 32 + dg] = a3;
}

// ---------------------------------------------------------------------------
// Fallback (ws-less): old 64-row in-place linear reading W directly.
// ---------------------------------------------------------------------------
__global__ __launch_bounds__(NT) void linear_kernel(
    float* __restrict__ io, const float* __restrict__ W)
{
    const int t = threadIdx.x;
    const int row0 = blockIdx.x * 64;
    __shared__ float P[64 * NC];
    const float* src = io + (size_t)row0 * NC;
    #pragma unroll
    for (int m = 0; m < 8; ++m) {
        const int e4 = m * NT + t;
        *(float4*)&P[e4 * 4] = *(const float4*)&src[e4 * 4];
    }
    __syncthreads();
    const int d = t & (NC - 1);
    const int rbase = (t >> 7) * 32;
    float acc[32];
    #pragma unroll
    for (int k = 0; k < 32; ++k) acc[k] = 0.f;
    const float* Wd = W + (size_t)d * NC;
    for (int c4 = 0; c4 < NC / 4; ++c4) {
        const float4 w = *(const float4*)(Wd + c4 * 4);
        #pragma unroll
        for (int k = 0; k < 32; ++k) {
            const float4 pv = *(const float4*)&P[(rbase + k) * NC + c4 * 4];
            acc[k] = fmaf(pv.x, w.x, acc[k]);
            acc[k] = fmaf(pv.y, w.y, acc[k]);
            acc[k] = fmaf(pv.z, w.z, acc[k]);
            acc[k] = fmaf(pv.w, w.w, acc[k]);
        }
    }
    #pragma unroll
    for (int k = 0; k < 32; ++k)
        io[(size_t)(row0 + rbase + k) * NC + d] = acc[k];
}

// ---------------------------------------------------------------------------
extern "C" void kernel_launch(void* const* d_in, const int* in_sizes, int n_in,
                              void* d_out, int out_size, void* d_ws, size_t ws_size,
                              hipStream_t stream) {
    const float* xyz   = nullptr;  // 49152
    const float* feats = nullptr;  // 2097152
    const float* W     = nullptr;  // 16384
    for (int k = 0; k < n_in; ++k) {
        if      (in_sizes[k] == NB * 3 * NP)       xyz   = (const float*)d_in[k];
        else if (in_sizes[k] == NB * NP * NC)      feats = (const float*)d_in[k];
        else if (in_sizes[k] == NC * NC)           W     = (const float*)d_in[k];
    }
    float* out = (float*)d_out;

    const size_t need = sizeof(float) * (size_t)(NC * NC);
    if (ws_size >= need) {
        float* Wt = (float*)d_ws;                  // 64 KiB
        knn_wave_kernel<<<NB * NP, 64, 0, stream>>>(xyz, feats, W, Wt, out);
        linear_v3_kernel<<<NB * NP / LROWS, NT, 0, stream>>>(out, Wt);
    } else {
        knn_wave_kernel<<<NB * NP, 64, 0, stream>>>(xyz, feats, W, nullptr, out);
        linear_kernel<<<NB * NP / 64, NT, 0, stream>>>(out, W);
    }
}